// Round 18
// baseline (184.419 us; speedup 1.0000x reference)
//
#include <hip/hip_runtime.h>
#include <stdint.h>

#define B_ 2
#define CTX_ 4096
#define DRAFT_ 512
#define D_ 2048
#define H_ 16
#define KVH_ 4
#define HD_ 128
#define TOT_ 4608
#define NSPLIT 8
#define SPLIT_LEN (TOT_ / NSPLIT)  // 576

using bf16x8 = __attribute__((ext_vector_type(8))) short;
using f32x4  = __attribute__((ext_vector_type(4))) float;
using f32x16 = __attribute__((ext_vector_type(16))) float;

__device__ __forceinline__ unsigned short f2bf(float x) {
  unsigned int u = __float_as_uint(x);
  u += 0x7fffu + ((u >> 16) & 1u);
  return (unsigned short)(u >> 16);
}

__device__ __forceinline__ unsigned cvtpk(float lo, float hi) {
  unsigned r;
  asm("v_cvt_pk_bf16_f32 %0, %1, %2" : "=v"(r) : "v"(lo), "v"(hi));
  return r;
}

__device__ __forceinline__ void gload16(const void* g, void* l) {
  __builtin_amdgcn_global_load_lds((const __attribute__((address_space(1))) void*)g,
                                   (__attribute__((address_space(3))) void*)l, 16, 0, 0);
}

__device__ __forceinline__ f32x16 vbroad16(float x) {
  f32x16 v;
#pragma unroll
  for (int i = 0; i < 16; ++i) v[i] = x;
  return v;
}

// ---------------------------------------------------------------------------
// Fused fp32 -> bf16 conversion: kv concat (context||draft per batch) + weights
// ---------------------------------------------------------------------------
__global__ __launch_bounds__(256, 4)
void conv_kernel(const float* __restrict__ ctx, const float* __restrict__ draft,
                 const float* __restrict__ wq, const float* __restrict__ wk,
                 const float* __restrict__ wv, const float* __restrict__ wo,
                 unsigned short* __restrict__ kv, unsigned short* __restrict__ wqb,
                 unsigned short* __restrict__ wkb, unsigned short* __restrict__ wvb,
                 unsigned short* __restrict__ wob) {
  long t = (long)blockIdx.x * 256 + threadIdx.x;
  const long NKV = (long)B_ * TOT_ * D_ / 8;  // 2359296
  const long NWQ = 2048L * 2048 / 8;          // 524288
  const long NWK = 512L * 2048 / 8;           // 131072
  const float* src;
  unsigned short* dst;
  if (t < NKV) {
    long i = t * 8;
    int b = (int)(i / ((long)TOT_ * D_));
    long rem = i - (long)b * TOT_ * D_;
    int r = (int)(rem / D_);
    int c = (int)(rem - (long)r * D_);
    if (r < CTX_) src = ctx + ((long)(b * CTX_ + r)) * D_ + c;
    else          src = draft + ((long)(b * DRAFT_ + (r - CTX_))) * D_ + c;
    dst = kv + i;
  } else if (t < NKV + NWQ) {
    long l = t - NKV; src = wq + l * 8; dst = wqb + l * 8;
  } else if (t < NKV + NWQ + NWK) {
    long l = t - NKV - NWQ; src = wk + l * 8; dst = wkb + l * 8;
  } else if (t < NKV + NWQ + 2 * NWK) {
    long l = t - NKV - NWQ - NWK; src = wv + l * 8; dst = wvb + l * 8;
  } else {
    long l = t - NKV - NWQ - 2 * NWK; src = wo + l * 8; dst = wob + l * 8;
  }
  float4 a = ((const float4*)src)[0];
  float4 b4 = ((const float4*)src)[1];
  uint4 o;
  o.x = (unsigned)f2bf(a.x) | ((unsigned)f2bf(a.y) << 16);
  o.y = (unsigned)f2bf(a.z) | ((unsigned)f2bf(a.w) << 16);
  o.z = (unsigned)f2bf(b4.x) | ((unsigned)f2bf(b4.y) << 16);
  o.w = (unsigned)f2bf(b4.z) | ((unsigned)f2bf(b4.w) << 16);
  *((uint4*)dst) = o;
}

// ---------------------------------------------------------------------------
// bf16 GEMM body, double-buffered with COUNTED vmcnt (no barrier drain).
// TO_LDS=true: stage acc into lds as fp32 [128][128] (BM=BN=128; 64 KB).
// ---------------------------------------------------------------------------
template <int BM, int BN, bool TO_LDS = false>
__device__ __forceinline__ void gemm_body(const unsigned short* __restrict__ A,
                                          const unsigned short* __restrict__ W,
                                          float* __restrict__ C, int ld, int kLen,
                                          int N, unsigned short* lds) {
  constexpr int MT = BM / 32;
  constexpr int NT = BN / 32;
  constexpr int BUF = (BM + BN) * 64;
  constexpr int LOADS = BM / 32 + BN / 32;  // gload16 per thread per K-step
  const int tid = threadIdx.x;
  const int lane = tid & 63, wid = tid >> 6;
  const int g = lane >> 4, r16 = lane & 15;
  const int wm = wid >> 1, wn = wid & 1;

  f32x4 zero = {0.f, 0.f, 0.f, 0.f};
  f32x4 acc[MT][NT];
#pragma unroll
  for (int i = 0; i < MT; ++i)
#pragma unroll
    for (int j = 0; j < NT; ++j) acc[i][j] = zero;

  auto stage = [&](int kb, unsigned short* buf) {
    unsigned short* As = buf;
    unsigned short* Bs = buf + BM * 64;
#pragma unroll
    for (int is = 0; is < BM / 32; ++is) {
      int row = is * 32 + (tid >> 3);
      int sl = (tid & 7) ^ (row & 7);
      gload16(A + (long)row * ld + kb + sl * 8, As + is * 2048 + wid * 512);
    }
#pragma unroll
    for (int is = 0; is < BN / 32; ++is) {
      int row = is * 32 + (tid >> 3);
      int sl = (tid & 7) ^ (row & 7);
      gload16(W + (long)row * ld + kb + sl * 8, Bs + is * 2048 + wid * 512);
    }
  };

  stage(0, lds);
  const int nk = kLen >> 6;
  for (int t = 0; t < nk; ++t) {
    if (t + 1 < nk) {
      stage((t + 1) << 6, lds + ((t + 1) & 1) * BUF);
      if constexpr (LOADS == 8)      asm volatile("s_waitcnt vmcnt(8)" ::: "memory");
      else if constexpr (LOADS == 6) asm volatile("s_waitcnt vmcnt(6)" ::: "memory");
      else if constexpr (LOADS == 4) asm volatile("s_waitcnt vmcnt(4)" ::: "memory");
      else                           asm volatile("s_waitcnt vmcnt(0)" ::: "memory");
    } else {
      asm volatile("s_waitcnt vmcnt(0)" ::: "memory");
    }
    __builtin_amdgcn_s_barrier();  // all waves' stage(t) landed
    __builtin_amdgcn_sched_barrier(0);
    unsigned short* As = lds + (t & 1) * BUF;
    unsigned short* Bs = As + BM * 64;
#pragma unroll
    for (int kh = 0; kh < 2; ++kh) {
      bf16x8 af[MT], bfr[NT];
#pragma unroll
      for (int i = 0; i < MT; ++i) {
        int row = wm * (BM / 2) + i * 16 + r16;
        int sl = (kh * 4 + g) ^ (row & 7);
        af[i] = *(const bf16x8*)(As + row * 64 + sl * 8);
      }
#pragma unroll
      for (int j = 0; j < NT; ++j) {
        int row = wn * (BN / 2) + j * 16 + r16;
        int sl = (kh * 4 + g) ^ (row & 7);
        bfr[j] = *(const bf16x8*)(Bs + row * 64 + sl * 8);
      }
#pragma unroll
      for (int i = 0; i < MT; ++i)
#pragma unroll
        for (int j = 0; j < NT; ++j)
          acc[i][j] = __builtin_amdgcn_mfma_f32_16x16x32_bf16(af[i], bfr[j], acc[i][j], 0, 0, 0);
    }
    __builtin_amdgcn_sched_barrier(0);
    __builtin_amdgcn_s_barrier();  // all waves done reading buf[t&1]
  }
  if constexpr (TO_LDS) {
    float* F = (float*)lds;  // [128][128] fp32 = 64 KB
#pragma unroll
    for (int i = 0; i < MT; ++i)
#pragma unroll
      for (int j = 0; j < NT; ++j)
#pragma unroll
        for (int e = 0; e < 4; ++e)
          F[(wm * 64 + i * 16 + g * 4 + e) * 128 + wn * 64 + j * 16 + r16] = acc[i][j][e];
  } else {
#pragma unroll
    for (int i = 0; i < MT; ++i)
#pragma unroll
      for (int j = 0; j < NT; ++j)
#pragma unroll
        for (int e = 0; e < 4; ++e) {
          int row = wm * (BM / 2) + i * 16 + g * 4 + e;
          int col = wn * (BN / 2) + j * 16 + r16;
          C[(long)row * N + col] = acc[i][j][e];
        }
  }
}

// ---------------------------------------------------------------------------
// QKV projection with XCD-chunked swizzle (704 = 8 XCD x 88).
// Q,K tiles -> fp32 raw (direct); V tiles -> TO_LDS + fused transpose+sigma
// epilogue (R17-verified).
// ---------------------------------------------------------------------------
__global__ __launch_bounds__(256, 2)
void qkv_kernel(const unsigned short* __restrict__ kvb,
                const unsigned short* __restrict__ wqb,
                const unsigned short* __restrict__ wkvb, float* __restrict__ qraw,
                float* __restrict__ kvraw, unsigned short* __restrict__ vt) {
  __shared__ unsigned short lds[2 * 256 * 64];  // 64 KB
  const int tid = threadIdx.x;
  int id = (blockIdx.x & 7) * 88 + (blockIdx.x >> 3);  // XCD-chunked
  if (id < 128) {
    int b = id >> 6, mb = (id >> 4) & 3, nb = id & 15;
    const unsigned short* A = kvb + ((long)b * TOT_ + CTX_ + mb * 128) * 2048;
    const unsigned short* W = wqb + (long)nb * 128 * 2048;
    float* C = qraw + ((long)b * 512 + mb * 128) * 2048 + nb * 128;
    gemm_body<128, 128>(A, W, C, 2048, 2048, 2048, lds);
  } else {
    int id2 = id - 128;
    int mb = id2 >> 3, nb = id2 & 7;
    const unsigned short* A = kvb + (long)mb * 128 * 2048;
    const unsigned short* W = wkvb + (long)nb * 128 * 2048;
    if (nb < 4) {
      float* C = kvraw + (long)mb * 128 * 1024 + nb * 128;
      gemm_body<128, 128>(A, W, C, 2048, 2048, 1024, lds);
    } else {
      gemm_body<128, 128, true>(A, W, nullptr, 2048, 2048, 0, lds);
      __syncthreads();
      // V epilogue: transpose + sigma key-permute from LDS
      float* F = (float*)lds;
      int bb = mb / 36;
      int sbase = (mb % 36) * 128;
      int kvh = nb - 4;
      int d = tid & 127;
      int g0 = tid >> 7;  // 0 or 1
      unsigned short* vrow = vt + ((long)((bb * KVH_ + kvh) * 128 + d)) * TOT_;
#pragma unroll
      for (int gi = 0; gi < 8; ++gi) {
        int s0 = (g0 + 2 * gi) * 8;  // 8-token group within tile
        unsigned o[4];
#pragma unroll
        for (int jj = 0; jj < 4; ++jj) {
          unsigned short lo = f2bf(F[(s0 + 2 * jj) * 128 + d]);
          unsigned short hi = f2bf(F[(s0 + 2 * jj + 1) * 128 + d]);
          o[jj] = (unsigned)lo | ((unsigned)hi << 16);
        }
        int k0 = s0 & 63;
        long dstbase = sbase + (s0 & ~63) + (k0 & 48) + ((k0 & 8) >> 1);
        *(uint2*)(vrow + dstbase) = make_uint2(o[0], o[1]);
        *(uint2*)(vrow + dstbase + 8) = make_uint2(o[2], o[3]);
      }
    }
  }
}

// ---------------------------------------------------------------------------
// O projection, DIRECT write to d_out: 64x64 tiles, 512 blocks.
// ---------------------------------------------------------------------------
__global__ __launch_bounds__(256, 3)
void ogemm_kernel(const unsigned short* __restrict__ attb,
                  const unsigned short* __restrict__ wob, float* __restrict__ out) {
  __shared__ unsigned short lds[2 * 128 * 64];  // 32 KB
  int sw = (blockIdx.x & 7) * 64 + (blockIdx.x >> 3);
  int nb = sw >> 4, mb = sw & 15;
  const unsigned short* A = attb + (long)mb * 64 * 2048;
  const unsigned short* W = wob + (long)nb * 64 * 2048;
  float* C = out + (long)mb * 64 * 2048 + nb * 64;
  gemm_body<64, 64>(A, W, C, 2048, 2048, 2048, lds);
}

// ---------------------------------------------------------------------------
// Post: Q RMSNorm+RoPE (+fold SCALE*log2e), K RMSNorm+RoPE. (V in qkv.)
// ---------------------------------------------------------------------------
__global__ __launch_bounds__(256, 4)
void post_kernel(const float* __restrict__ qraw, const float* __restrict__ kvraw,
                 const float* __restrict__ qw, const float* __restrict__ kw,
                 const int* __restrict__ cpos, const int* __restrict__ dpos,
                 unsigned short* __restrict__ qatt, unsigned short* __restrict__ katt) {
  const int QB = (B_ * DRAFT_ * H_) / 4;  // 4096
  int bid = blockIdx.x;
  int tid = threadIdx.x;
  int lane = tid & 63, wid = tid >> 6;
  bool isQ = (bid < QB);
  int row = (isQ ? bid : bid - QB) * 4 + wid;
  const float* src;
  const float* wnorm;
  int pos;
  float fold;
  unsigned short* dst;
  if (isQ) {
    int b = row >> 13;
    int r2 = row & 8191;
    int s = r2 >> 4, hh = r2 & 15;
    src = qraw + (long)row * 128;
    wnorm = qw;
    pos = dpos[b * DRAFT_ + s];
    fold = 0.08838834764831843f * 1.4426950408889634f;  // SCALE * log2(e)
    dst = qatt + ((long)(b * H_ + hh) * DRAFT_ + s) * 128;
  } else {
    int b = row / (TOT_ * KVH_);
    int r2 = row - b * (TOT_ * KVH_);
    int s = r2 >> 2, hh = r2 & 3;
    src = kvraw + ((long)(b * TOT_ + s)) * 1024 + hh * 128;
    wnorm = kw;
    pos = (s < CTX_) ? cpos[b * CTX_ + s] : dpos[b * DRAFT_ + (s - CTX_)];
    fold = 1.0f;
    dst = katt + ((long)(b * KVH_ + hh) * TOT_ + s) * 128;
  }
  float x1 = src[lane], x2 = src[lane + 64];
  float ss = x1 * x1 + x2 * x2;
#pragma unroll
  for (int off = 1; off < 64; off <<= 1) ss += __shfl_xor(ss, off);
  float rn = rsqrtf(ss * 0.0078125f + 1e-6f);
  float y1 = wnorm[lane] * x1 * rn;
  float y2 = wnorm[lane + 64] * x2 * rn;
  float invf = exp2f((float)lane * -0.20762050593046014f);  // 10000^(-lane/64)
  float fr = (float)pos * invf;
  float sn, cs;
  sincosf(fr, &sn, &cs);
  dst[lane] = f2bf((y1 * cs - y2 * sn) * fold);
  dst[lane + 64] = f2bf((y2 * cs + y1 * sn) * fold);
}

// ---------------------------------------------------------------------------
// Flash attention v9: 512-thread blocks, split-K x8 -> grid 512 = 2 blocks/CU
// EXACT (16 waves/CU -- R13's intent finally delivered; grid 256 was only
// 1 block/CU). XCD chunks of 64 blocks = exactly 2 z-groups (z-aligned,
// 2.36 MB K/V L2-fit). 32x32x16 MFMA, identity P-repack (sigma-permuted V),
// MAX-FREE softmax, K+V dbuf gload_lds counted vmcnt, PV-split softmax.
// ---------------------------------------------------------------------------
__global__ __launch_bounds__(512, 2)
void attn_kernel(const unsigned short* __restrict__ Q, const unsigned short* __restrict__ Kt,
                 const unsigned short* __restrict__ Vt, float* __restrict__ pOa,
                 float* __restrict__ pOb, float* __restrict__ pL) {
  __shared__ unsigned short lds[2 * 16384];  // 64 KB (2 x (K 16KB + V 16KB))
  const int tid = threadIdx.x, lane = tid & 63, wid = tid >> 6;
  const int hi = lane >> 5, l31 = lane & 31;
  // XCD-chunked block swizzle: 512 = 8 XCD x 64; each XCD = 2 z-groups.
  int sw = ((blockIdx.x & 7) << 6) | (blockIdx.x >> 3);
  const int q0 = sw & 1, h = (sw >> 1) & 15, z = sw >> 5;  // z in [0,16)
  const int b = z >> 3, split = z & 7;
  const int kvh = h >> 2;
  const float M = 16.4f;

  const unsigned short* Qb =
      Q + ((long)(b * H_ + h) * DRAFT_ + q0 * 256 + wid * 32) * 128;
  bf16x8 qf[8];
#pragma unroll
  for (int ks = 0; ks < 8; ++ks)
    qf[ks] = *(const bf16x8*)(Qb + l31 * 128 + ks * 16 + hi * 8);

  f32x16 acc[4];
#pragma unroll
  for (int nb = 0; nb < 4; ++nb) acc[nb] = vbroad16(0.f);
  float l_run = 0.0f;

  const unsigned short* Kbase = Kt + (long)(b * KVH_ + kvh) * TOT_ * 128;
  const unsigned short* Vbase = Vt + (long)(b * KVH_ + kvh) * 128L * TOT_;

  // 512-thread staging: 2 passes each for K and V; 4 gload16 per thread.
  auto stage = [&](int s0, int c) {
    unsigned short* Ks = lds + c * 16384;
    unsigned short* Vs = Ks + 8192;
#pragma unroll
    for (int is = 0; is < 2; ++is) {
      int row = is * 32 + (tid >> 4);
      int sl = (tid & 15) ^ (row & 7);
      gload16(Kbase + (long)(s0 + row) * 128 + sl * 8, Ks + is * 4096 + wid * 512);
    }
#pragma unroll
    for (int is = 0; is < 2; ++is) {
      int d = is * 64 + (tid >> 3);
      int sl = (tid & 7) ^ (d & 7);
      gload16(Vbase + (long)d * TOT_ + s0 + sl * 8, Vs + is * 4096 + wid * 512);
    }
  };

  const int sBeg = split * SPLIT_LEN;
  const int NTile = SPLIT_LEN / 64;  // 9
  stage(sBeg, 0);
  int cur = 0;
  for (int t = 0; t < NTile; ++t) {
    if (t + 1 < NTile) {
      stage(sBeg + (t + 1) * 64, cur ^ 1);  // 4 loads stay in flight
      asm volatile("s_waitcnt vmcnt(4)" ::: "memory");
    } else {
      asm volatile("s_waitcnt vmcnt(0)" ::: "memory");
    }
    __builtin_amdgcn_s_barrier();
    __builtin_amdgcn_sched_barrier(0);
    const char* KsB = (const char*)(lds + cur * 16384);
    const char* VsB = KsB + 16384;

    // S^T = K_tile * Q : D[key][q=l31]; C-init = -M (max-free softmax)
    f32x16 st0 = vbroad16(-M), st1 = vbroad16(-M);
    __builtin_amdgcn_s_setprio(1);
#pragma unroll
    for (int ks = 0; ks < 8; ++ks) {
      int gsl = ks * 2 + hi;
      bf16x8 a0 = *(const bf16x8*)(KsB + l31 * 256 + ((gsl ^ (l31 & 7)) * 16));
      bf16x8 a1 = *(const bf16x8*)(KsB + (32 + l31) * 256 + ((gsl ^ (l31 & 7)) * 16));
      st0 = __builtin_amdgcn_mfma_f32_32x32x16_bf16(a0, qf[ks], st0, 0, 0, 0);
      st1 = __builtin_amdgcn_mfma_f32_32x32x16_bf16(a1, qf[ks], st1, 0, 0, 0);
    }
    __builtin_amdgcn_s_setprio(0);

    // softmax on st0 (keys 0..31) -> PV B-operands pf01 (identity repack)
    float l_own = 0.0f;
    unsigned pkA[8];
#pragma unroll
    for (int m = 0; m < 8; ++m) {
      float e0 = exp2f(st0[2 * m]), e1 = exp2f(st0[2 * m + 1]);
      l_own += e0 + e1;
      pkA[m] = cvtpk(e0, e1);
    }
    union { unsigned u[4]; bf16x8 v; } pf01[2], pf23[2];
#pragma unroll
    for (int m = 0; m < 4; ++m) {
      pf01[0].u[m] = pkA[m];
      pf01[1].u[m] = pkA[m + 4];
    }
    // PV batch 1 (key slots 0..31) issues first ...
    __builtin_amdgcn_s_setprio(1);
#pragma unroll
    for (int nb = 0; nb < 4; ++nb) {
      int d = nb * 32 + l31;
#pragma unroll
      for (int k2 = 0; k2 < 2; ++k2) {
        bf16x8 a = *(const bf16x8*)(VsB + d * 128 + (((k2 * 2 + hi) ^ (d & 7)) * 16));
        acc[nb] = __builtin_amdgcn_mfma_f32_32x32x16_bf16(a, pf01[k2].v, acc[nb], 0, 0, 0);
      }
    }
    __builtin_amdgcn_sched_barrier(0);
    // ... softmax st1 VALU runs under batch-1's in-flight MFMAs
    unsigned pkB[8];
#pragma unroll
    for (int m = 0; m < 8; ++m) {
      float e0 = exp2f(st1[2 * m]), e1 = exp2f(st1[2 * m + 1]);
      l_own += e0 + e1;
      pkB[m] = cvtpk(e0, e1);
    }
#pragma unroll
    for (int m = 0; m < 4; ++m) {
      pf23[0].u[m] = pkB[m];
      pf23[1].u[m] = pkB[m + 4];
    }
    l_run += l_own;
    // PV batch 2 (key slots 32..63)
#pragma unroll
    for (int nb = 0; nb < 4; ++nb) {
      int d = nb * 32 + l31;
#pragma unroll
      for (int k2 = 0; k2 < 2; ++k2) {
        bf16x8 a = *(const bf16x8*)(VsB + d * 128 + ((((k2 + 2) * 2 + hi) ^ (d & 7)) * 16));
        acc[nb] = __builtin_amdgcn_mfma_f32_32x32x16_bf16(a, pf23[k2].v, acc[nb], 0, 0, 0);
      }
    }
    __builtin_amdgcn_s_setprio(0);
    __builtin_amdgcn_sched_barrier(0);
    __builtin_amdgcn_s_barrier();  // all waves done with buf[cur]
    cur ^= 1;
  }
  l_run += __shfl_xor(l_run, 32);  // add partner half's key sum

  const long R = (long)B_ * H_ * DRAFT_;
  const int q = q0 * 256 + wid * 32 + l31;
  const long rowIdx = ((long)(b * H_ + h)) * DRAFT_ + q;
  float* pO = (split < 4) ? pOa : pOb;
  const long pbase = ((long)(split & 3) * R + rowIdx) * 128;
#pragma unroll
  for (int nb = 0; nb < 4; ++nb)
#pragma unroll
    for (int r4 = 0; r4 < 4; ++r4) {
      int d0 = nb * 32 + 8 * r4 + 4 * hi;
      float4 v = make_float4(acc[nb][4 * r4 + 0], acc[nb][4 * r4 + 1],
                             acc[nb][4 * r4 + 2], acc[nb][4 * r4 + 3]);
      *(float4*)(pO + pbase + d0) = v;
    }
  if (hi == 0) pL[(long)split * R + rowIdx] = l_run;
}

// ---------------------------------------------------------------------------
// Combine split-K partials over 8 splits from two buffers (plain sum).
// ---------------------------------------------------------------------------
__global__ __launch_bounds__(256, 4)
void acomb_kernel(const float* __restrict__ pOa, const float* __restrict__ pOb,
                  const float* __restrict__ pL, unsigned short* __restrict__ attb) {
  const long R = (long)B_ * H_ * DRAFT_;  // 16384
  int row = blockIdx.x * 2 + (threadIdx.x >> 7);
  int d = threadIdx.x & 127;
  float ltot = 0.0f, o = 0.0f;
#pragma unroll
  for (int i = 0; i < 4; ++i) {
    ltot += pL[(long)i * R + row];
    o += pOa[((long)i * R + row) * 128 + d];
  }
#pragma unroll
  for (int i = 0; i < 4; ++i) {
    ltot += pL[(long)(i + 4) * R + row];
    o += pOb[((long)i * R + row) * 128 + d];
  }
  o /= ltot;
  int bh = row >> 9, q = row & 511;
  int b = bh >> 4, h = bh & 15;
  attb[(((long)(b * 512 + q) * 16 + h)) * 128 + d] = f2bf(o);
}

// ---------------------------------------------------------------------------
extern "C" void kernel_launch(void* const* d_in, const int* in_sizes, int n_in,
                              void* d_out, int out_size, void* d_ws, size_t ws_size,
                              hipStream_t stream) {
  const float* draft = (const float*)d_in[0];
  const float* ctx = (const float*)d_in[1];
  const float* Wq = (const float*)d_in[2];
  const float* Wk = (const float*)d_in[3];
  const float* Wv = (const float*)d_in[4];
  const float* Wo = (const float*)d_in[5];
  const float* qw = (const float*)d_in[6];
  const float* kw = (const float*)d_in[7];
  const int* cpos = (const int*)d_in[8];
  const int* dpos = (const int*)d_in[9];

  char* ws = (char*)d_ws;
  unsigned short* kvb = (unsigned short*)(ws + 0);          // 37,748,736 (dead after qkv)
  float* pOa = (float*)(ws + 0);                            // 33,554,432 (aliases kvb)
  unsigned short* wqb = (unsigned short*)(ws + 37748736);   //  8,388,608
  unsigned short* wkb = (unsigned short*)(ws + 46137344);   //  2,097,152 \ adjacent =
  unsigned short* wvb = (unsigned short*)(ws + 48234496);   //  2,097,152 / wkvb[1024,2048]
  unsigned short* wob = (unsigned short*)(ws + 50331648);   //  8,388,608
  float* qraw = (float*)(ws + 58720256);                    //  8,388,608 (dead after post)
  float* kvraw = (float*)(ws + 67108864);                   // 37,748,736 (dead after post)
  float* pOb = (float*)(ws + 67108864);                     // 33,554,432 (aliases kvraw)
  float* pL = (float*)(ws + 100663296);                     //     524,288
  unsigned short* qatt = (unsigned short*)(ws + 104857600); //  4,194,304
  unsigned short* katt = (unsigned short*)(ws + 109051904); //  9,437,184
  unsigned short* vtb = (unsigned short*)(ws + 118489088);  //  9,437,184
  unsigned short* attb = (unsigned short*)(ws + 127926272); //  4,194,304
  // total 132,120,576 B

  // 1. convert inputs/weights to bf16 (kv = context||draft per batch)
  conv_kernel<<<dim3(14336), 256, 0, stream>>>(ctx, draft, Wq, Wk, Wv, Wo, kvb, wqb,
                                               wkb, wvb, wob);
  // 2. Q/K/V projections; V fused transpose epilogue (Q,K -> fp32 raw)
  qkv_kernel<<<dim3(704), 256, 0, stream>>>(kvb, wqb, wkb, qraw, kvraw, vtb);
  // 3. RMSNorm+RoPE for Q,K only
  post_kernel<<<dim3(13312), 256, 0, stream>>>(qraw, kvraw, qw, kw, cpos, dpos, qatt,
                                               katt);
  // 4. attention: 512 blocks x 512 threads = 2/CU exact, 16 waves/CU
  attn_kernel<<<dim3(512), 512, 0, stream>>>(qatt, katt, vtb, pOa, pOb, pL);
  // 5. combine partials (plain sum over 8 splits)
  acomb_kernel<<<dim3(8192), 256, 0, stream>>>(pOa, pOb, pL, attb);
  // 6. out = attn @ Wo^T, direct 64x64 tiles
  ogemm_kernel<<<dim3(512), 256, 0, stream>>>(attb, wob, (float*)d_out);
}

// Round 19
// 171.999 us; speedup vs baseline: 1.0722x; 1.0722x over previous
//
#include <hip/hip_runtime.h>
#include <stdint.h>

#define B_ 2
#define CTX_ 4096
#define DRAFT_ 512
#define D_ 2048
#define H_ 16
#define KVH_ 4
#define HD_ 128
#define TOT_ 4608
#define NSPLIT 4
#define SPLIT_LEN (TOT_ / NSPLIT)  // 1152

using bf16x8 = __attribute__((ext_vector_type(8))) short;
using f32x4  = __attribute__((ext_vector_type(4))) float;
using f32x16 = __attribute__((ext_vector_type(16))) float;

__device__ __forceinline__ unsigned short f2bf(float x) {
  unsigned int u = __float_as_uint(x);
  u += 0x7fffu + ((u >> 16) & 1u);
  return (unsigned short)(u >> 16);
}

__device__ __forceinline__ unsigned cvtpk(float lo, float hi) {
  unsigned r;
  asm("v_cvt_pk_bf16_f32 %0, %1, %2" : "=v"(r) : "v"(lo), "v"(hi));
  return r;
}

__device__ __forceinline__ void gload16(const void* g, void* l) {
  __builtin_amdgcn_global_load_lds((const __attribute__((address_space(1))) void*)g,
                                   (__attribute__((address_space(3))) void*)l, 16, 0, 0);
}

__device__ __forceinline__ f32x16 vbroad16(float x) {
  f32x16 v;
#pragma unroll
  for (int i = 0; i < 16; ++i) v[i] = x;
  return v;
}

// ---------------------------------------------------------------------------
// Fused fp32 -> bf16 conversion: kv concat (context||draft per batch) + weights
// ---------------------------------------------------------------------------
__global__ __launch_bounds__(256, 4)
void conv_kernel(const float* __restrict__ ctx, const float* __restrict__ draft,
                 const float* __restrict__ wq, const float* __restrict__ wk,
                 const float* __restrict__ wv, const float* __restrict__ wo,
                 unsigned short* __restrict__ kv, unsigned short* __restrict__ wqb,
                 unsigned short* __restrict__ wkb, unsigned short* __restrict__ wvb,
                 unsigned short* __restrict__ wob) {
  long t = (long)blockIdx.x * 256 + threadIdx.x;
  const long NKV = (long)B_ * TOT_ * D_ / 8;  // 2359296
  const long NWQ = 2048L * 2048 / 8;          // 524288
  const long NWK = 512L * 2048 / 8;           // 131072
  const float* src;
  unsigned short* dst;
  if (t < NKV) {
    long i = t * 8;
    int b = (int)(i / ((long)TOT_ * D_));
    long rem = i - (long)b * TOT_ * D_;
    int r = (int)(rem / D_);
    int c = (int)(rem - (long)r * D_);
    if (r < CTX_) src = ctx + ((long)(b * CTX_ + r)) * D_ + c;
    else          src = draft + ((long)(b * DRAFT_ + (r - CTX_))) * D_ + c;
    dst = kv + i;
  } else if (t < NKV + NWQ) {
    long l = t - NKV; src = wq + l * 8; dst = wqb + l * 8;
  } else if (t < NKV + NWQ + NWK) {
    long l = t - NKV - NWQ; src = wk + l * 8; dst = wkb + l * 8;
  } else if (t < NKV + NWQ + 2 * NWK) {
    long l = t - NKV - NWQ - NWK; src = wv + l * 8; dst = wvb + l * 8;
  } else {
    long l = t - NKV - NWQ - 2 * NWK; src = wo + l * 8; dst = wob + l * 8;
  }
  float4 a = ((const float4*)src)[0];
  float4 b4 = ((const float4*)src)[1];
  uint4 o;
  o.x = (unsigned)f2bf(a.x) | ((unsigned)f2bf(a.y) << 16);
  o.y = (unsigned)f2bf(a.z) | ((unsigned)f2bf(a.w) << 16);
  o.z = (unsigned)f2bf(b4.x) | ((unsigned)f2bf(b4.y) << 16);
  o.w = (unsigned)f2bf(b4.z) | ((unsigned)f2bf(b4.w) << 16);
  *((uint4*)dst) = o;
}

// ---------------------------------------------------------------------------
// bf16 GEMM body, double-buffered with COUNTED vmcnt (no barrier drain).
// TO_LDS=true: stage acc into lds as fp32 [128][128] (BM=BN=128; 64 KB).
// ---------------------------------------------------------------------------
template <int BM, int BN, bool TO_LDS = false>
__device__ __forceinline__ void gemm_body(const unsigned short* __restrict__ A,
                                          const unsigned short* __restrict__ W,
                                          float* __restrict__ C, int ld, int kLen,
                                          int N, unsigned short* lds) {
  constexpr int MT = BM / 32;
  constexpr int NT = BN / 32;
  constexpr int BUF = (BM + BN) * 64;
  constexpr int LOADS = BM / 32 + BN / 32;  // gload16 per thread per K-step
  const int tid = threadIdx.x;
  const int lane = tid & 63, wid = tid >> 6;
  const int g = lane >> 4, r16 = lane & 15;
  const int wm = wid >> 1, wn = wid & 1;

  f32x4 zero = {0.f, 0.f, 0.f, 0.f};
  f32x4 acc[MT][NT];
#pragma unroll
  for (int i = 0; i < MT; ++i)
#pragma unroll
    for (int j = 0; j < NT; ++j) acc[i][j] = zero;

  auto stage = [&](int kb, unsigned short* buf) {
    unsigned short* As = buf;
    unsigned short* Bs = buf + BM * 64;
#pragma unroll
    for (int is = 0; is < BM / 32; ++is) {
      int row = is * 32 + (tid >> 3);
      int sl = (tid & 7) ^ (row & 7);
      gload16(A + (long)row * ld + kb + sl * 8, As + is * 2048 + wid * 512);
    }
#pragma unroll
    for (int is = 0; is < BN / 32; ++is) {
      int row = is * 32 + (tid >> 3);
      int sl = (tid & 7) ^ (row & 7);
      gload16(W + (long)row * ld + kb + sl * 8, Bs + is * 2048 + wid * 512);
    }
  };

  stage(0, lds);
  const int nk = kLen >> 6;
  for (int t = 0; t < nk; ++t) {
    if (t + 1 < nk) {
      stage((t + 1) << 6, lds + ((t + 1) & 1) * BUF);
      if constexpr (LOADS == 8)      asm volatile("s_waitcnt vmcnt(8)" ::: "memory");
      else if constexpr (LOADS == 6) asm volatile("s_waitcnt vmcnt(6)" ::: "memory");
      else if constexpr (LOADS == 4) asm volatile("s_waitcnt vmcnt(4)" ::: "memory");
      else                           asm volatile("s_waitcnt vmcnt(0)" ::: "memory");
    } else {
      asm volatile("s_waitcnt vmcnt(0)" ::: "memory");
    }
    __builtin_amdgcn_s_barrier();  // all waves' stage(t) landed
    __builtin_amdgcn_sched_barrier(0);
    unsigned short* As = lds + (t & 1) * BUF;
    unsigned short* Bs = As + BM * 64;
#pragma unroll
    for (int kh = 0; kh < 2; ++kh) {
      bf16x8 af[MT], bfr[NT];
#pragma unroll
      for (int i = 0; i < MT; ++i) {
        int row = wm * (BM / 2) + i * 16 + r16;
        int sl = (kh * 4 + g) ^ (row & 7);
        af[i] = *(const bf16x8*)(As + row * 64 + sl * 8);
      }
#pragma unroll
      for (int j = 0; j < NT; ++j) {
        int row = wn * (BN / 2) + j * 16 + r16;
        int sl = (kh * 4 + g) ^ (row & 7);
        bfr[j] = *(const bf16x8*)(Bs + row * 64 + sl * 8);
      }
#pragma unroll
      for (int i = 0; i < MT; ++i)
#pragma unroll
        for (int j = 0; j < NT; ++j)
          acc[i][j] = __builtin_amdgcn_mfma_f32_16x16x32_bf16(af[i], bfr[j], acc[i][j], 0, 0, 0);
    }
    __builtin_amdgcn_sched_barrier(0);
    __builtin_amdgcn_s_barrier();  // all waves done reading buf[t&1]
  }
  if constexpr (TO_LDS) {
    float* F = (float*)lds;  // [128][128] fp32 = 64 KB
#pragma unroll
    for (int i = 0; i < MT; ++i)
#pragma unroll
      for (int j = 0; j < NT; ++j)
#pragma unroll
        for (int e = 0; e < 4; ++e)
          F[(wm * 64 + i * 16 + g * 4 + e) * 128 + wn * 64 + j * 16 + r16] = acc[i][j][e];
  } else {
#pragma unroll
    for (int i = 0; i < MT; ++i)
#pragma unroll
      for (int j = 0; j < NT; ++j)
#pragma unroll
        for (int e = 0; e < 4; ++e) {
          int row = wm * (BM / 2) + i * 16 + g * 4 + e;
          int col = wn * (BN / 2) + j * 16 + r16;
          C[(long)row * N + col] = acc[i][j][e];
        }
  }
}

// ---------------------------------------------------------------------------
// QKV projection with XCD-chunked swizzle (704 = 8 XCD x 88).
// Q,K tiles -> fp32 raw (direct); V tiles -> TO_LDS + fused transpose+sigma
// epilogue (R17-verified).
// ---------------------------------------------------------------------------
__global__ __launch_bounds__(256, 2)
void qkv_kernel(const unsigned short* __restrict__ kvb,
                const unsigned short* __restrict__ wqb,
                const unsigned short* __restrict__ wkvb, float* __restrict__ qraw,
                float* __restrict__ kvraw, unsigned short* __restrict__ vt) {
  __shared__ unsigned short lds[2 * 256 * 64];  // 64 KB
  const int tid = threadIdx.x;
  int id = (blockIdx.x & 7) * 88 + (blockIdx.x >> 3);  // XCD-chunked
  if (id < 128) {
    int b = id >> 6, mb = (id >> 4) & 3, nb = id & 15;
    const unsigned short* A = kvb + ((long)b * TOT_ + CTX_ + mb * 128) * 2048;
    const unsigned short* W = wqb + (long)nb * 128 * 2048;
    float* C = qraw + ((long)b * 512 + mb * 128) * 2048 + nb * 128;
    gemm_body<128, 128>(A, W, C, 2048, 2048, 2048, lds);
  } else {
    int id2 = id - 128;
    int mb = id2 >> 3, nb = id2 & 7;
    const unsigned short* A = kvb + (long)mb * 128 * 2048;
    const unsigned short* W = wkvb + (long)nb * 128 * 2048;
    if (nb < 4) {
      float* C = kvraw + (long)mb * 128 * 1024 + nb * 128;
      gemm_body<128, 128>(A, W, C, 2048, 2048, 1024, lds);
    } else {
      gemm_body<128, 128, true>(A, W, nullptr, 2048, 2048, 0, lds);
      __syncthreads();
      // V epilogue: transpose + sigma key-permute from LDS
      float* F = (float*)lds;
      int bb = mb / 36;
      int sbase = (mb % 36) * 128;
      int kvh = nb - 4;
      int d = tid & 127;
      int g0 = tid >> 7;  // 0 or 1
      unsigned short* vrow = vt + ((long)((bb * KVH_ + kvh) * 128 + d)) * TOT_;
#pragma unroll
      for (int gi = 0; gi < 8; ++gi) {
        int s0 = (g0 + 2 * gi) * 8;  // 8-token group within tile
        unsigned o[4];
#pragma unroll
        for (int jj = 0; jj < 4; ++jj) {
          unsigned short lo = f2bf(F[(s0 + 2 * jj) * 128 + d]);
          unsigned short hi = f2bf(F[(s0 + 2 * jj + 1) * 128 + d]);
          o[jj] = (unsigned)lo | ((unsigned)hi << 16);
        }
        int k0 = s0 & 63;
        long dstbase = sbase + (s0 & ~63) + (k0 & 48) + ((k0 & 8) >> 1);
        *(uint2*)(vrow + dstbase) = make_uint2(o[0], o[1]);
        *(uint2*)(vrow + dstbase + 8) = make_uint2(o[2], o[3]);
      }
    }
  }
}

// ---------------------------------------------------------------------------
// O projection, DIRECT write to d_out: 64x64 tiles, 512 blocks.
// ---------------------------------------------------------------------------
__global__ __launch_bounds__(256, 3)
void ogemm_kernel(const unsigned short* __restrict__ attb,
                  const unsigned short* __restrict__ wob, float* __restrict__ out) {
  __shared__ unsigned short lds[2 * 128 * 64];  // 32 KB
  int sw = (blockIdx.x & 7) * 64 + (blockIdx.x >> 3);
  int nb = sw >> 4, mb = sw & 15;
  const unsigned short* A = attb + (long)mb * 64 * 2048;
  const unsigned short* W = wob + (long)nb * 64 * 2048;
  float* C = out + (long)mb * 64 * 2048 + nb * 64;
  gemm_body<64, 64>(A, W, C, 2048, 2048, 2048, lds);
}

// ---------------------------------------------------------------------------
// Post: Q RMSNorm+RoPE (+fold SCALE*log2e), K RMSNorm+RoPE. (V in qkv.)
// ---------------------------------------------------------------------------
__global__ __launch_bounds__(256, 4)
void post_kernel(const float* __restrict__ qraw, const float* __restrict__ kvraw,
                 const float* __restrict__ qw, const float* __restrict__ kw,
                 const int* __restrict__ cpos, const int* __restrict__ dpos,
                 unsigned short* __restrict__ qatt, unsigned short* __restrict__ katt) {
  const int QB = (B_ * DRAFT_ * H_) / 4;  // 4096
  int bid = blockIdx.x;
  int tid = threadIdx.x;
  int lane = tid & 63, wid = tid >> 6;
  bool isQ = (bid < QB);
  int row = (isQ ? bid : bid - QB) * 4 + wid;
  const float* src;
  const float* wnorm;
  int pos;
  float fold;
  unsigned short* dst;
  if (isQ) {
    int b = row >> 13;
    int r2 = row & 8191;
    int s = r2 >> 4, hh = r2 & 15;
    src = qraw + (long)row * 128;
    wnorm = qw;
    pos = dpos[b * DRAFT_ + s];
    fold = 0.08838834764831843f * 1.4426950408889634f;  // SCALE * log2(e)
    dst = qatt + ((long)(b * H_ + hh) * DRAFT_ + s) * 128;
  } else {
    int b = row / (TOT_ * KVH_);
    int r2 = row - b * (TOT_ * KVH_);
    int s = r2 >> 2, hh = r2 & 3;
    src = kvraw + ((long)(b * TOT_ + s)) * 1024 + hh * 128;
    wnorm = kw;
    pos = (s < CTX_) ? cpos[b * CTX_ + s] : dpos[b * DRAFT_ + (s - CTX_)];
    fold = 1.0f;
    dst = katt + ((long)(b * KVH_ + hh) * TOT_ + s) * 128;
  }
  float x1 = src[lane], x2 = src[lane + 64];
  float ss = x1 * x1 + x2 * x2;
#pragma unroll
  for (int off = 1; off < 64; off <<= 1) ss += __shfl_xor(ss, off);
  float rn = rsqrtf(ss * 0.0078125f + 1e-6f);
  float y1 = wnorm[lane] * x1 * rn;
  float y2 = wnorm[lane + 64] * x2 * rn;
  float invf = exp2f((float)lane * -0.20762050593046014f);  // 10000^(-lane/64)
  float fr = (float)pos * invf;
  float sn, cs;
  sincosf(fr, &sn, &cs);
  dst[lane] = f2bf((y1 * cs - y2 * sn) * fold);
  dst[lane + 64] = f2bf((y2 * cs + y1 * sn) * fold);
}

// ---------------------------------------------------------------------------
// Flash attention (R17, verified): 512-thread blocks, split-K x4, grid 256 =
// 8 XCD x 32 (z == XCD, 2.36 MB K/V L2-fit, no tail). 32x32x16 MFMA,
// identity P-repack (sigma-permuted V), MAX-FREE softmax, K+V double-buffered
// gload_lds with counted vmcnt, PV-split softmax.
// ---------------------------------------------------------------------------
__global__ __launch_bounds__(512, 2)
void attn_kernel(const unsigned short* __restrict__ Q, const unsigned short* __restrict__ Kt,
                 const unsigned short* __restrict__ Vt, float* __restrict__ pO,
                 float* __restrict__ pL) {
  __shared__ unsigned short lds[2 * 16384];  // 64 KB (2 x (K 16KB + V 16KB))
  const int tid = threadIdx.x, lane = tid & 63, wid = tid >> 6;
  const int hi = lane >> 5, l31 = lane & 31;
  // XCD-chunked block swizzle: 256 = 8 XCD x 32; z == XCD.
  int sw = ((blockIdx.x & 7) << 5) | (blockIdx.x >> 3);
  const int q0 = sw & 1, h = (sw >> 1) & 15, z = sw >> 5;  // z in [0,8)
  const int b = z >> 2, split = z & 3;
  const int kvh = h >> 2;
  const float M = 16.4f;

  const unsigned short* Qb =
      Q + ((long)(b * H_ + h) * DRAFT_ + q0 * 256 + wid * 32) * 128;
  bf16x8 qf[8];
#pragma unroll
  for (int ks = 0; ks < 8; ++ks)
    qf[ks] = *(const bf16x8*)(Qb + l31 * 128 + ks * 16 + hi * 8);

  f32x16 acc[4];
#pragma unroll
  for (int nb = 0; nb < 4; ++nb) acc[nb] = vbroad16(0.f);
  float l_run = 0.0f;

  const unsigned short* Kbase = Kt + (long)(b * KVH_ + kvh) * TOT_ * 128;
  const unsigned short* Vbase = Vt + (long)(b * KVH_ + kvh) * 128L * TOT_;

  // 512-thread staging: 2 passes each for K and V; 4 gload16 per thread.
  auto stage = [&](int s0, int c) {
    unsigned short* Ks = lds + c * 16384;
    unsigned short* Vs = Ks + 8192;
#pragma unroll
    for (int is = 0; is < 2; ++is) {
      int row = is * 32 + (tid >> 4);
      int sl = (tid & 15) ^ (row & 7);
      gload16(Kbase + (long)(s0 + row) * 128 + sl * 8, Ks + is * 4096 + wid * 512);
    }
#pragma unroll
    for (int is = 0; is < 2; ++is) {
      int d = is * 64 + (tid >> 3);
      int sl = (tid & 7) ^ (d & 7);
      gload16(Vbase + (long)d * TOT_ + s0 + sl * 8, Vs + is * 4096 + wid * 512);
    }
  };

  const int sBeg = split * SPLIT_LEN;
  const int NTile = SPLIT_LEN / 64;  // 18
  stage(sBeg, 0);
  int cur = 0;
  for (int t = 0; t < NTile; ++t) {
    if (t + 1 < NTile) {
      stage(sBeg + (t + 1) * 64, cur ^ 1);  // 4 loads stay in flight
      asm volatile("s_waitcnt vmcnt(4)" ::: "memory");
    } else {
      asm volatile("s_waitcnt vmcnt(0)" ::: "memory");
    }
    __builtin_amdgcn_s_barrier();
    __builtin_amdgcn_sched_barrier(0);
    const char* KsB = (const char*)(lds + cur * 16384);
    const char* VsB = KsB + 16384;

    // S^T = K_tile * Q : D[key][q=l31]; C-init = -M (max-free softmax)
    f32x16 st0 = vbroad16(-M), st1 = vbroad16(-M);
    __builtin_amdgcn_s_setprio(1);
#pragma unroll
    for (int ks = 0; ks < 8; ++ks) {
      int gsl = ks * 2 + hi;
      bf16x8 a0 = *(const bf16x8*)(KsB + l31 * 256 + ((gsl ^ (l31 & 7)) * 16));
      bf16x8 a1 = *(const bf16x8*)(KsB + (32 + l31) * 256 + ((gsl ^ (l31 & 7)) * 16));
      st0 = __builtin_amdgcn_mfma_f32_32x32x16_bf16(a0, qf[ks], st0, 0, 0, 0);
      st1 = __builtin_amdgcn_mfma_f32_32x32x16_bf16(a1, qf[ks], st1, 0, 0, 0);
    }
    __builtin_amdgcn_s_setprio(0);

    // softmax on st0 (keys 0..31) -> PV B-operands pf01 (identity repack)
    float l_own = 0.0f;
    unsigned pkA[8];
#pragma unroll
    for (int m = 0; m < 8; ++m) {
      float e0 = exp2f(st0[2 * m]), e1 = exp2f(st0[2 * m + 1]);
      l_own += e0 + e1;
      pkA[m] = cvtpk(e0, e1);
    }
    union { unsigned u[4]; bf16x8 v; } pf01[2], pf23[2];
#pragma unroll
    for (int m = 0; m < 4; ++m) {
      pf01[0].u[m] = pkA[m];
      pf01[1].u[m] = pkA[m + 4];
    }
    // PV batch 1 (key slots 0..31) issues first ...
    __builtin_amdgcn_s_setprio(1);
#pragma unroll
    for (int nb = 0; nb < 4; ++nb) {
      int d = nb * 32 + l31;
#pragma unroll
      for (int k2 = 0; k2 < 2; ++k2) {
        bf16x8 a = *(const bf16x8*)(VsB + d * 128 + (((k2 * 2 + hi) ^ (d & 7)) * 16));
        acc[nb] = __builtin_amdgcn_mfma_f32_32x32x16_bf16(a, pf01[k2].v, acc[nb], 0, 0, 0);
      }
    }
    __builtin_amdgcn_sched_barrier(0);
    // ... softmax st1 VALU runs under batch-1's in-flight MFMAs
    unsigned pkB[8];
#pragma unroll
    for (int m = 0; m < 8; ++m) {
      float e0 = exp2f(st1[2 * m]), e1 = exp2f(st1[2 * m + 1]);
      l_own += e0 + e1;
      pkB[m] = cvtpk(e0, e1);
    }
#pragma unroll
    for (int m = 0; m < 4; ++m) {
      pf23[0].u[m] = pkB[m];
      pf23[1].u[m] = pkB[m + 4];
    }
    l_run += l_own;
    // PV batch 2 (key slots 32..63)
#pragma unroll
    for (int nb = 0; nb < 4; ++nb) {
      int d = nb * 32 + l31;
#pragma unroll
      for (int k2 = 0; k2 < 2; ++k2) {
        bf16x8 a = *(const bf16x8*)(VsB + d * 128 + ((((k2 + 2) * 2 + hi) ^ (d & 7)) * 16));
        acc[nb] = __builtin_amdgcn_mfma_f32_32x32x16_bf16(a, pf23[k2].v, acc[nb], 0, 0, 0);
      }
    }
    __builtin_amdgcn_s_setprio(0);
    __builtin_amdgcn_sched_barrier(0);
    __builtin_amdgcn_s_barrier();  // all waves done with buf[cur]
    cur ^= 1;
  }
  l_run += __shfl_xor(l_run, 32);  // add partner half's key sum

  const long R = (long)B_ * H_ * DRAFT_;
  const int q = q0 * 256 + wid * 32 + l31;
  const long rowIdx = ((long)(b * H_ + h)) * DRAFT_ + q;
  const long pbase = ((long)split * R + rowIdx) * 128;
#pragma unroll
  for (int nb = 0; nb < 4; ++nb)
#pragma unroll
    for (int r4 = 0; r4 < 4; ++r4) {
      int d0 = nb * 32 + 8 * r4 + 4 * hi;
      float4 v = make_float4(acc[nb][4 * r4 + 0], acc[nb][4 * r4 + 1],
                             acc[nb][4 * r4 + 2], acc[nb][4 * r4 + 3]);
      *(float4*)(pO + pbase + d0) = v;
    }
  if (hi == 0) pL[(long)split * R + rowIdx] = l_run;
}

// ---------------------------------------------------------------------------
// Combine split-K partials (same fixed M for all splits -> plain sum).
// ---------------------------------------------------------------------------
__global__ __launch_bounds__(256, 4)
void acomb_kernel(const float* __restrict__ pO, const float* __restrict__ pL,
                  unsigned short* __restrict__ attb) {
  const long R = (long)B_ * H_ * DRAFT_;  // 16384
  int row = blockIdx.x * 2 + (threadIdx.x >> 7);
  int d = threadIdx.x & 127;
  float ltot = 0.0f, o = 0.0f;
#pragma unroll
  for (int i = 0; i < NSPLIT; ++i) {
    ltot += pL[(long)i * R + row];
    o += pO[((long)i * R + row) * 128 + d];
  }
  o /= ltot;
  int bh = row >> 9, q = row & 511;
  int b = bh >> 4, h = bh & 15;
  attb[(((long)(b * 512 + q) * 16 + h)) * 128 + d] = f2bf(o);
}

// ---------------------------------------------------------------------------
extern "C" void kernel_launch(void* const* d_in, const int* in_sizes, int n_in,
                              void* d_out, int out_size, void* d_ws, size_t ws_size,
                              hipStream_t stream) {
  const float* draft = (const float*)d_in[0];
  const float* ctx = (const float*)d_in[1];
  const float* Wq = (const float*)d_in[2];
  const float* Wk = (const float*)d_in[3];
  const float* Wv = (const float*)d_in[4];
  const float* Wo = (const float*)d_in[5];
  const float* qw = (const float*)d_in[6];
  const float* kw = (const float*)d_in[7];
  const int* cpos = (const int*)d_in[8];
  const int* dpos = (const int*)d_in[9];

  char* ws = (char*)d_ws;
  unsigned short* kvb = (unsigned short*)(ws + 0);          // 37,748,736
  unsigned short* wqb = (unsigned short*)(ws + 37748736);   //  8,388,608
  unsigned short* wkb = (unsigned short*)(ws + 46137344);   //  2,097,152 \ adjacent =
  unsigned short* wvb = (unsigned short*)(ws + 48234496);   //  2,097,152 / wkvb[1024,2048]
  unsigned short* wob = (unsigned short*)(ws + 50331648);   //  8,388,608
  float* qraw = (float*)(ws + 58720256);                    //  8,388,608
  float* kvraw = (float*)(ws + 67108864);                   // 37,748,736 (K cols only; dead after post)
  float* pO = (float*)(ws + 67108864);                      // 33,554,432 (aliases kvraw)
  float* pL = (float*)(ws + 100663296);                     //     262,144
  unsigned short* qatt = (unsigned short*)(ws + 104857600); //  4,194,304
  unsigned short* katt = (unsigned short*)(ws + 109051904); //  9,437,184
  unsigned short* vtb = (unsigned short*)(ws + 118489088);  //  9,437,184
  unsigned short* attb = (unsigned short*)(ws + 127926272); //  4,194,304
  // total 132,120,576 B

  // 1. convert inputs/weights to bf16 (kv = context||draft per batch)
  conv_kernel<<<dim3(14336), 256, 0, stream>>>(ctx, draft, Wq, Wk, Wv, Wo, kvb, wqb,
                                               wkb, wvb, wob);
  // 2. Q/K/V projections; V fused transpose epilogue (Q,K -> fp32 raw)
  qkv_kernel<<<dim3(704), 256, 0, stream>>>(kvb, wqb, wkb, qraw, kvraw, vtb);
  // 3. RMSNorm+RoPE for Q,K only
  post_kernel<<<dim3(13312), 256, 0, stream>>>(qraw, kvraw, qw, kw, cpos, dpos, qatt,
                                               katt);
  // 4. attention: 256 blocks x 512 threads, split-K x4
  attn_kernel<<<dim3(256), 512, 0, stream>>>(qatt, katt, vtb, pO, pL);
  // 5. combine partials (plain sum)
  acomb_kernel<<<dim3(8192), 256, 0, stream>>>(pO, pL, attb);
  // 6. out = attn @ Wo^T, direct 64x64 tiles
  ogemm_kernel<<<dim3(512), 256, 0, stream>>>(attb, wob, (float*)d_out);
}

// Round 20
// 167.700 us; speedup vs baseline: 1.0997x; 1.0256x over previous
//
#include <hip/hip_runtime.h>
#include <stdint.h>

#define B_ 2
#define CTX_ 4096
#define DRAFT_ 512
#define D_ 2048
#define H_ 16
#define KVH_ 4
#define HD_ 128
#define TOT_ 4608
#define NSPLIT 4
#define SPLIT_LEN (TOT_ / NSPLIT)  // 1152

using bf16x8 = __attribute__((ext_vector_type(8))) short;
using f32x4  = __attribute__((ext_vector_type(4))) float;
using f32x16 = __attribute__((ext_vector_type(16))) float;

__device__ __forceinline__ unsigned short f2bf(float x) {
  unsigned int u = __float_as_uint(x);
  u += 0x7fffu + ((u >> 16) & 1u);
  return (unsigned short)(u >> 16);
}

__device__ __forceinline__ unsigned cvtpk(float lo, float hi) {
  unsigned r;
  asm("v_cvt_pk_bf16_f32 %0, %1, %2" : "=v"(r) : "v"(lo), "v"(hi));
  return r;
}

__device__ __forceinline__ void gload16(const void* g, void* l) {
  __builtin_amdgcn_global_load_lds((const __attribute__((address_space(1))) void*)g,
                                   (__attribute__((address_space(3))) void*)l, 16, 0, 0);
}

__device__ __forceinline__ f32x16 vbroad16(float x) {
  f32x16 v;
#pragma unroll
  for (int i = 0; i < 16; ++i) v[i] = x;
  return v;
}

// ---------------------------------------------------------------------------
// Fused fp32 -> bf16 conversion: kv concat (context||draft per batch) + weights
// ---------------------------------------------------------------------------
__global__ __launch_bounds__(256, 4)
void conv_kernel(const float* __restrict__ ctx, const float* __restrict__ draft,
                 const float* __restrict__ wq, const float* __restrict__ wk,
                 const float* __restrict__ wv, const float* __restrict__ wo,
                 unsigned short* __restrict__ kv, unsigned short* __restrict__ wqb,
                 unsigned short* __restrict__ wkb, unsigned short* __restrict__ wvb,
                 unsigned short* __restrict__ wob) {
  long t = (long)blockIdx.x * 256 + threadIdx.x;
  const long NKV = (long)B_ * TOT_ * D_ / 8;  // 2359296
  const long NWQ = 2048L * 2048 / 8;          // 524288
  const long NWK = 512L * 2048 / 8;           // 131072
  const float* src;
  unsigned short* dst;
  if (t < NKV) {
    long i = t * 8;
    int b = (int)(i / ((long)TOT_ * D_));
    long rem = i - (long)b * TOT_ * D_;
    int r = (int)(rem / D_);
    int c = (int)(rem - (long)r * D_);
    if (r < CTX_) src = ctx + ((long)(b * CTX_ + r)) * D_ + c;
    else          src = draft + ((long)(b * DRAFT_ + (r - CTX_))) * D_ + c;
    dst = kv + i;
  } else if (t < NKV + NWQ) {
    long l = t - NKV; src = wq + l * 8; dst = wqb + l * 8;
  } else if (t < NKV + NWQ + NWK) {
    long l = t - NKV - NWQ; src = wk + l * 8; dst = wkb + l * 8;
  } else if (t < NKV + NWQ + 2 * NWK) {
    long l = t - NKV - NWQ - NWK; src = wv + l * 8; dst = wvb + l * 8;
  } else {
    long l = t - NKV - NWQ - 2 * NWK; src = wo + l * 8; dst = wob + l * 8;
  }
  float4 a = ((const float4*)src)[0];
  float4 b4 = ((const float4*)src)[1];
  uint4 o;
  o.x = (unsigned)f2bf(a.x) | ((unsigned)f2bf(a.y) << 16);
  o.y = (unsigned)f2bf(a.z) | ((unsigned)f2bf(a.w) << 16);
  o.z = (unsigned)f2bf(b4.x) | ((unsigned)f2bf(b4.y) << 16);
  o.w = (unsigned)f2bf(b4.z) | ((unsigned)f2bf(b4.w) << 16);
  *((uint4*)dst) = o;
}

// ---------------------------------------------------------------------------
// bf16 GEMM body (R12-verified), full double buffer, counted vmcnt.
// Used by ogemm only now.
// ---------------------------------------------------------------------------
template <int BM, int BN>
__device__ __forceinline__ void gemm_body(const unsigned short* __restrict__ A,
                                          const unsigned short* __restrict__ W,
                                          float* __restrict__ C, int ld, int kLen,
                                          int N, unsigned short* lds) {
  constexpr int MT = BM / 32;
  constexpr int NT = BN / 32;
  constexpr int BUF = (BM + BN) * 64;
  constexpr int LOADS = BM / 32 + BN / 32;
  const int tid = threadIdx.x;
  const int lane = tid & 63, wid = tid >> 6;
  const int g = lane >> 4, r16 = lane & 15;
  const int wm = wid >> 1, wn = wid & 1;

  f32x4 zero = {0.f, 0.f, 0.f, 0.f};
  f32x4 acc[MT][NT];
#pragma unroll
  for (int i = 0; i < MT; ++i)
#pragma unroll
    for (int j = 0; j < NT; ++j) acc[i][j] = zero;

  auto stage = [&](int kb, unsigned short* buf) {
    unsigned short* As = buf;
    unsigned short* Bs = buf + BM * 64;
#pragma unroll
    for (int is = 0; is < BM / 32; ++is) {
      int row = is * 32 + (tid >> 3);
      int sl = (tid & 7) ^ (row & 7);
      gload16(A + (long)row * ld + kb + sl * 8, As + is * 2048 + wid * 512);
    }
#pragma unroll
    for (int is = 0; is < BN / 32; ++is) {
      int row = is * 32 + (tid >> 3);
      int sl = (tid & 7) ^ (row & 7);
      gload16(W + (long)row * ld + kb + sl * 8, Bs + is * 2048 + wid * 512);
    }
  };

  stage(0, lds);
  const int nk = kLen >> 6;
  for (int t = 0; t < nk; ++t) {
    if (t + 1 < nk) {
      stage((t + 1) << 6, lds + ((t + 1) & 1) * BUF);
      if constexpr (LOADS == 8)      asm volatile("s_waitcnt vmcnt(8)" ::: "memory");
      else if constexpr (LOADS == 6) asm volatile("s_waitcnt vmcnt(6)" ::: "memory");
      else if constexpr (LOADS == 4) asm volatile("s_waitcnt vmcnt(4)" ::: "memory");
      else                           asm volatile("s_waitcnt vmcnt(0)" ::: "memory");
    } else {
      asm volatile("s_waitcnt vmcnt(0)" ::: "memory");
    }
    __builtin_amdgcn_s_barrier();
    __builtin_amdgcn_sched_barrier(0);
    unsigned short* As = lds + (t & 1) * BUF;
    unsigned short* Bs = As + BM * 64;
#pragma unroll
    for (int kh = 0; kh < 2; ++kh) {
      bf16x8 af[MT], bfr[NT];
#pragma unroll
      for (int i = 0; i < MT; ++i) {
        int row = wm * (BM / 2) + i * 16 + r16;
        int sl = (kh * 4 + g) ^ (row & 7);
        af[i] = *(const bf16x8*)(As + row * 64 + sl * 8);
      }
#pragma unroll
      for (int j = 0; j < NT; ++j) {
        int row = wn * (BN / 2) + j * 16 + r16;
        int sl = (kh * 4 + g) ^ (row & 7);
        bfr[j] = *(const bf16x8*)(Bs + row * 64 + sl * 8);
      }
#pragma unroll
      for (int i = 0; i < MT; ++i)
#pragma unroll
        for (int j = 0; j < NT; ++j)
          acc[i][j] = __builtin_amdgcn_mfma_f32_16x16x32_bf16(af[i], bfr[j], acc[i][j], 0, 0, 0);
    }
    __builtin_amdgcn_sched_barrier(0);
    __builtin_amdgcn_s_barrier();
  }
#pragma unroll
  for (int i = 0; i < MT; ++i)
#pragma unroll
    for (int j = 0; j < NT; ++j)
#pragma unroll
      for (int e = 0; e < 4; ++e) {
        int row = wm * (BM / 2) + i * 16 + g * 4 + e;
        int col = wn * (BN / 2) + j * 16 + r16;
        C[(long)row * N + col] = acc[i][j][e];
      }
}

// ---------------------------------------------------------------------------
// qkv GEMM body: 128x128, BK=64, A DOUBLE-buffered + B SINGLE-buffered
// (B re-staged from L2 every K-step either way; single buffer is safe since
// the trailing barrier of step t-1 orders all B(t-1) reads before stageB(t)).
// LDS = 48 KB -> 3 blocks/CU (vs 2), killing the 704-vs-512 ragged tail.
// Per-wave FIFO at the wait: [A(t):4, B(t):4, A(t+1):4] -> vmcnt(4).
// TO_LDS: store acc as BF16 F[128][128] (32 KB, fits in the A-dbuf region).
// ---------------------------------------------------------------------------
template <bool TO_LDS>
__device__ __forceinline__ void gemm_qkv(const unsigned short* __restrict__ A,
                                         const unsigned short* __restrict__ W,
                                         float* __restrict__ C, int N,
                                         unsigned short* lds) {
  const int tid = threadIdx.x;
  const int lane = tid & 63, wid = tid >> 6;
  const int g = lane >> 4, r16 = lane & 15;
  const int wm = wid >> 1, wn = wid & 1;

  f32x4 zero = {0.f, 0.f, 0.f, 0.f};
  f32x4 acc[4][4];
#pragma unroll
  for (int i = 0; i < 4; ++i)
#pragma unroll
    for (int j = 0; j < 4; ++j) acc[i][j] = zero;

  auto stageA = [&](int kb, int c) {
#pragma unroll
    for (int is = 0; is < 4; ++is) {
      int row = is * 32 + (tid >> 3);
      int sl = (tid & 7) ^ (row & 7);
      gload16(A + (long)row * 2048 + kb + sl * 8, lds + c * 8192 + is * 2048 + wid * 512);
    }
  };
  auto stageB = [&](int kb) {
#pragma unroll
    for (int is = 0; is < 4; ++is) {
      int row = is * 32 + (tid >> 3);
      int sl = (tid & 7) ^ (row & 7);
      gload16(W + (long)row * 2048 + kb + sl * 8, lds + 16384 + is * 2048 + wid * 512);
    }
  };

  stageA(0, 0);
  for (int t = 0; t < 32; ++t) {
    stageB(t << 6);
    if (t + 1 < 32) {
      stageA((t + 1) << 6, (t + 1) & 1);
      asm volatile("s_waitcnt vmcnt(4)" ::: "memory");  // A(t)+B(t) landed
    } else {
      asm volatile("s_waitcnt vmcnt(0)" ::: "memory");
    }
    __builtin_amdgcn_s_barrier();
    __builtin_amdgcn_sched_barrier(0);
    const unsigned short* As = lds + (t & 1) * 8192;
    const unsigned short* Bs = lds + 16384;
#pragma unroll
    for (int kh = 0; kh < 2; ++kh) {
      bf16x8 af[4], bfr[4];
#pragma unroll
      for (int i = 0; i < 4; ++i) {
        int row = wm * 64 + i * 16 + r16;
        int sl = (kh * 4 + g) ^ (row & 7);
        af[i] = *(const bf16x8*)(As + row * 64 + sl * 8);
      }
#pragma unroll
      for (int j = 0; j < 4; ++j) {
        int row = wn * 64 + j * 16 + r16;
        int sl = (kh * 4 + g) ^ (row & 7);
        bfr[j] = *(const bf16x8*)(Bs + row * 64 + sl * 8);
      }
#pragma unroll
      for (int i = 0; i < 4; ++i)
#pragma unroll
        for (int j = 0; j < 4; ++j)
          acc[i][j] = __builtin_amdgcn_mfma_f32_16x16x32_bf16(af[i], bfr[j], acc[i][j], 0, 0, 0);
    }
    __builtin_amdgcn_sched_barrier(0);
    __builtin_amdgcn_s_barrier();  // all waves done reading A buf + B buf
  }
  if constexpr (TO_LDS) {
    unsigned short* Fb = lds;  // bf16 [128][128] = 32 KB (A-dbuf region)
#pragma unroll
    for (int i = 0; i < 4; ++i)
#pragma unroll
      for (int j = 0; j < 4; ++j)
#pragma unroll
        for (int e = 0; e < 4; ++e)
          Fb[(wm * 64 + i * 16 + g * 4 + e) * 128 + wn * 64 + j * 16 + r16] =
              f2bf(acc[i][j][e]);
  } else {
#pragma unroll
    for (int i = 0; i < 4; ++i)
#pragma unroll
      for (int j = 0; j < 4; ++j)
#pragma unroll
        for (int e = 0; e < 4; ++e) {
          int row = wm * 64 + i * 16 + g * 4 + e;
          int col = wn * 64 + j * 16 + r16;
          C[(long)row * N + col] = acc[i][j][e];
        }
  }
}

// ---------------------------------------------------------------------------
// QKV projection with XCD-chunked swizzle (704 = 8 XCD x 88), 48 KB LDS ->
// 3 blocks/CU (single occupancy round). Q,K tiles -> fp32 raw; V tiles ->
// bf16-LDS + fused transpose+sigma epilogue.
// ---------------------------------------------------------------------------
__global__ __launch_bounds__(256, 3)
void qkv_kernel(const unsigned short* __restrict__ kvb,
                const unsigned short* __restrict__ wqb,
                const unsigned short* __restrict__ wkvb, float* __restrict__ qraw,
                float* __restrict__ kvraw, unsigned short* __restrict__ vt) {
  __shared__ unsigned short lds[24576];  // 48 KB: A dbuf 2x16KB + B 16KB
  const int tid = threadIdx.x;
  int id = (blockIdx.x & 7) * 88 + (blockIdx.x >> 3);  // XCD-chunked
  if (id < 128) {
    int b = id >> 6, mb = (id >> 4) & 3, nb = id & 15;
    const unsigned short* A = kvb + ((long)b * TOT_ + CTX_ + mb * 128) * 2048;
    const unsigned short* W = wqb + (long)nb * 128 * 2048;
    float* C = qraw + ((long)b * 512 + mb * 128) * 2048 + nb * 128;
    gemm_qkv<false>(A, W, C, 2048, lds);
  } else {
    int id2 = id - 128;
    int mb = id2 >> 3, nb = id2 & 7;
    const unsigned short* A = kvb + (long)mb * 128 * 2048;
    const unsigned short* W = wkvb + (long)nb * 128 * 2048;
    if (nb < 4) {
      float* C = kvraw + (long)mb * 128 * 1024 + nb * 128;
      gemm_qkv<false>(A, W, C, 1024, lds);
    } else {
      gemm_qkv<true>(A, W, nullptr, 0, lds);
      __syncthreads();
      // V epilogue: transpose + sigma key-permute from bf16 LDS
      const unsigned short* Fb = lds;
      int bb = mb / 36;
      int sbase = (mb % 36) * 128;
      int kvh = nb - 4;
      int d = tid & 127;
      int g0 = tid >> 7;  // 0 or 1
      unsigned short* vrow = vt + ((long)((bb * KVH_ + kvh) * 128 + d)) * TOT_;
#pragma unroll
      for (int gi = 0; gi < 8; ++gi) {
        int s0 = (g0 + 2 * gi) * 8;  // 8-token group within tile
        unsigned o[4];
#pragma unroll
        for (int jj = 0; jj < 4; ++jj) {
          unsigned short lo = Fb[(s0 + 2 * jj) * 128 + d];
          unsigned short hi = Fb[(s0 + 2 * jj + 1) * 128 + d];
          o[jj] = (unsigned)lo | ((unsigned)hi << 16);
        }
        int k0 = s0 & 63;
        long dstbase = sbase + (s0 & ~63) + (k0 & 48) + ((k0 & 8) >> 1);
        *(uint2*)(vrow + dstbase) = make_uint2(o[0], o[1]);
        *(uint2*)(vrow + dstbase + 8) = make_uint2(o[2], o[3]);
      }
    }
  }
}

// ---------------------------------------------------------------------------
// O projection, DIRECT write to d_out: 64x64 tiles, 512 blocks.
// ---------------------------------------------------------------------------
__global__ __launch_bounds__(256, 3)
void ogemm_kernel(const unsigned short* __restrict__ attb,
                  const unsigned short* __restrict__ wob, float* __restrict__ out) {
  __shared__ unsigned short lds[2 * 128 * 64];  // 32 KB
  int sw = (blockIdx.x & 7) * 64 + (blockIdx.x >> 3);
  int nb = sw >> 4, mb = sw & 15;
  const unsigned short* A = attb + (long)mb * 64 * 2048;
  const unsigned short* W = wob + (long)nb * 64 * 2048;
  float* C = out + (long)mb * 64 * 2048 + nb * 64;
  gemm_body<64, 64>(A, W, C, 2048, 2048, 2048, lds);
}

// ---------------------------------------------------------------------------
// Post: Q RMSNorm+RoPE (+fold SCALE*log2e), K RMSNorm+RoPE. (V in qkv.)
// ---------------------------------------------------------------------------
__global__ __launch_bounds__(256, 4)
void post_kernel(const float* __restrict__ qraw, const float* __restrict__ kvraw,
                 const float* __restrict__ qw, const float* __restrict__ kw,
                 const int* __restrict__ cpos, const int* __restrict__ dpos,
                 unsigned short* __restrict__ qatt, unsigned short* __restrict__ katt) {
  const int QB = (B_ * DRAFT_ * H_) / 4;  // 4096
  int bid = blockIdx.x;
  int tid = threadIdx.x;
  int lane = tid & 63, wid = tid >> 6;
  bool isQ = (bid < QB);
  int row = (isQ ? bid : bid - QB) * 4 + wid;
  const float* src;
  const float* wnorm;
  int pos;
  float fold;
  unsigned short* dst;
  if (isQ) {
    int b = row >> 13;
    int r2 = row & 8191;
    int s = r2 >> 4, hh = r2 & 15;
    src = qraw + (long)row * 128;
    wnorm = qw;
    pos = dpos[b * DRAFT_ + s];
    fold = 0.08838834764831843f * 1.4426950408889634f;  // SCALE * log2(e)
    dst = qatt + ((long)(b * H_ + hh) * DRAFT_ + s) * 128;
  } else {
    int b = row / (TOT_ * KVH_);
    int r2 = row - b * (TOT_ * KVH_);
    int s = r2 >> 2, hh = r2 & 3;
    src = kvraw + ((long)(b * TOT_ + s)) * 1024 + hh * 128;
    wnorm = kw;
    pos = (s < CTX_) ? cpos[b * CTX_ + s] : dpos[b * DRAFT_ + (s - CTX_)];
    fold = 1.0f;
    dst = katt + ((long)(b * KVH_ + hh) * TOT_ + s) * 128;
  }
  float x1 = src[lane], x2 = src[lane + 64];
  float ss = x1 * x1 + x2 * x2;
#pragma unroll
  for (int off = 1; off < 64; off <<= 1) ss += __shfl_xor(ss, off);
  float rn = rsqrtf(ss * 0.0078125f + 1e-6f);
  float y1 = wnorm[lane] * x1 * rn;
  float y2 = wnorm[lane + 64] * x2 * rn;
  float invf = exp2f((float)lane * -0.20762050593046014f);  // 10000^(-lane/64)
  float fr = (float)pos * invf;
  float sn, cs;
  sincosf(fr, &sn, &cs);
  dst[lane] = f2bf((y1 * cs - y2 * sn) * fold);
  dst[lane + 64] = f2bf((y2 * cs + y1 * sn) * fold);
}

// ---------------------------------------------------------------------------
// Flash attention (R17, verified): 512-thread blocks, split-K x4, grid 256 =
// 8 XCD x 32 (z == XCD, 2.36 MB K/V L2-fit, no tail). 32x32x16 MFMA,
// identity P-repack (sigma-permuted V), MAX-FREE softmax, K+V double-buffered
// gload_lds with counted vmcnt, PV-split softmax.
// ---------------------------------------------------------------------------
__global__ __launch_bounds__(512, 2)
void attn_kernel(const unsigned short* __restrict__ Q, const unsigned short* __restrict__ Kt,
                 const unsigned short* __restrict__ Vt, float* __restrict__ pO,
                 float* __restrict__ pL) {
  __shared__ unsigned short lds[2 * 16384];  // 64 KB (2 x (K 16KB + V 16KB))
  const int tid = threadIdx.x, lane = tid & 63, wid = tid >> 6;
  const int hi = lane >> 5, l31 = lane & 31;
  // XCD-chunked block swizzle: 256 = 8 XCD x 32; z == XCD.
  int sw = ((blockIdx.x & 7) << 5) | (blockIdx.x >> 3);
  const int q0 = sw & 1, h = (sw >> 1) & 15, z = sw >> 5;  // z in [0,8)
  const int b = z >> 2, split = z & 3;
  const int kvh = h >> 2;
  const float M = 16.4f;

  const unsigned short* Qb =
      Q + ((long)(b * H_ + h) * DRAFT_ + q0 * 256 + wid * 32) * 128;
  bf16x8 qf[8];
#pragma unroll
  for (int ks = 0; ks < 8; ++ks)
    qf[ks] = *(const bf16x8*)(Qb + l31 * 128 + ks * 16 + hi * 8);

  f32x16 acc[4];
#pragma unroll
  for (int nb = 0; nb < 4; ++nb) acc[nb] = vbroad16(0.f);
  float l_run = 0.0f;

  const unsigned short* Kbase = Kt + (long)(b * KVH_ + kvh) * TOT_ * 128;
  const unsigned short* Vbase = Vt + (long)(b * KVH_ + kvh) * 128L * TOT_;

  // 512-thread staging: 2 passes each for K and V; 4 gload16 per thread.
  auto stage = [&](int s0, int c) {
    unsigned short* Ks = lds + c * 16384;
    unsigned short* Vs = Ks + 8192;
#pragma unroll
    for (int is = 0; is < 2; ++is) {
      int row = is * 32 + (tid >> 4);
      int sl = (tid & 15) ^ (row & 7);
      gload16(Kbase + (long)(s0 + row) * 128 + sl * 8, Ks + is * 4096 + wid * 512);
    }
#pragma unroll
    for (int is = 0; is < 2; ++is) {
      int d = is * 64 + (tid >> 3);
      int sl = (tid & 7) ^ (d & 7);
      gload16(Vbase + (long)d * TOT_ + s0 + sl * 8, Vs + is * 4096 + wid * 512);
    }
  };

  const int sBeg = split * SPLIT_LEN;
  const int NTile = SPLIT_LEN / 64;  // 18
  stage(sBeg, 0);
  int cur = 0;
  for (int t = 0; t < NTile; ++t) {
    if (t + 1 < NTile) {
      stage(sBeg + (t + 1) * 64, cur ^ 1);  // 4 loads stay in flight
      asm volatile("s_waitcnt vmcnt(4)" ::: "memory");
    } else {
      asm volatile("s_waitcnt vmcnt(0)" ::: "memory");
    }
    __builtin_amdgcn_s_barrier();
    __builtin_amdgcn_sched_barrier(0);
    const char* KsB = (const char*)(lds + cur * 16384);
    const char* VsB = KsB + 16384;

    // S^T = K_tile * Q : D[key][q=l31]; C-init = -M (max-free softmax)
    f32x16 st0 = vbroad16(-M), st1 = vbroad16(-M);
    __builtin_amdgcn_s_setprio(1);
#pragma unroll
    for (int ks = 0; ks < 8; ++ks) {
      int gsl = ks * 2 + hi;
      bf16x8 a0 = *(const bf16x8*)(KsB + l31 * 256 + ((gsl ^ (l31 & 7)) * 16));
      bf16x8 a1 = *(const bf16x8*)(KsB + (32 + l31) * 256 + ((gsl ^ (l31 & 7)) * 16));
      st0 = __builtin_amdgcn_mfma_f32_32x32x16_bf16(a0, qf[ks], st0, 0, 0, 0);
      st1 = __builtin_amdgcn_mfma_f32_32x32x16_bf16(a1, qf[ks], st1, 0, 0, 0);
    }
    __builtin_amdgcn_s_setprio(0);

    // softmax on st0 (keys 0..31) -> PV B-operands pf01 (identity repack)
    float l_own = 0.0f;
    unsigned pkA[8];
#pragma unroll
    for (int m = 0; m < 8; ++m) {
      float e0 = exp2f(st0[2 * m]), e1 = exp2f(st0[2 * m + 1]);
      l_own += e0 + e1;
      pkA[m] = cvtpk(e0, e1);
    }
    union { unsigned u[4]; bf16x8 v; } pf01[2], pf23[2];
#pragma unroll
    for (int m = 0; m < 4; ++m) {
      pf01[0].u[m] = pkA[m];
      pf01[1].u[m] = pkA[m + 4];
    }
    // PV batch 1 (key slots 0..31) issues first ...
    __builtin_amdgcn_s_setprio(1);
#pragma unroll
    for (int nb = 0; nb < 4; ++nb) {
      int d = nb * 32 + l31;
#pragma unroll
      for (int k2 = 0; k2 < 2; ++k2) {
        bf16x8 a = *(const bf16x8*)(VsB + d * 128 + (((k2 * 2 + hi) ^ (d & 7)) * 16));
        acc[nb] = __builtin_amdgcn_mfma_f32_32x32x16_bf16(a, pf01[k2].v, acc[nb], 0, 0, 0);
      }
    }
    __builtin_amdgcn_sched_barrier(0);
    // ... softmax st1 VALU runs under batch-1's in-flight MFMAs
    unsigned pkB[8];
#pragma unroll
    for (int m = 0; m < 8; ++m) {
      float e0 = exp2f(st1[2 * m]), e1 = exp2f(st1[2 * m + 1]);
      l_own += e0 + e1;
      pkB[m] = cvtpk(e0, e1);
    }
#pragma unroll
    for (int m = 0; m < 4; ++m) {
      pf23[0].u[m] = pkB[m];
      pf23[1].u[m] = pkB[m + 4];
    }
    l_run += l_own;
    // PV batch 2 (key slots 32..63)
#pragma unroll
    for (int nb = 0; nb < 4; ++nb) {
      int d = nb * 32 + l31;
#pragma unroll
      for (int k2 = 0; k2 < 2; ++k2) {
        bf16x8 a = *(const bf16x8*)(VsB + d * 128 + ((((k2 + 2) * 2 + hi) ^ (d & 7)) * 16));
        acc[nb] = __builtin_amdgcn_mfma_f32_32x32x16_bf16(a, pf23[k2].v, acc[nb], 0, 0, 0);
      }
    }
    __builtin_amdgcn_s_setprio(0);
    __builtin_amdgcn_sched_barrier(0);
    __builtin_amdgcn_s_barrier();  // all waves done with buf[cur]
    cur ^= 1;
  }
  l_run += __shfl_xor(l_run, 32);  // add partner half's key sum

  const long R = (long)B_ * H_ * DRAFT_;
  const int q = q0 * 256 + wid * 32 + l31;
  const long rowIdx = ((long)(b * H_ + h)) * DRAFT_ + q;
  const long pbase = ((long)split * R + rowIdx) * 128;
#pragma unroll
  for (int nb = 0; nb < 4; ++nb)
#pragma unroll
    for (int r4 = 0; r4 < 4; ++r4) {
      int d0 = nb * 32 + 8 * r4 + 4 * hi;
      float4 v = make_float4(acc[nb][4 * r4 + 0], acc[nb][4 * r4 + 1],
                             acc[nb][4 * r4 + 2], acc[nb][4 * r4 + 3]);
      *(float4*)(pO + pbase + d0) = v;
    }
  if (hi == 0) pL[(long)split * R + rowIdx] = l_run;
}

// ---------------------------------------------------------------------------
// Combine split-K partials (same fixed M for all splits -> plain sum).
// ---------------------------------------------------------------------------
__global__ __launch_bounds__(256, 4)
void acomb_kernel(const float* __restrict__ pO, const float* __restrict__ pL,
                  unsigned short* __restrict__ attb) {
  const long R = (long)B_ * H_ * DRAFT_;  // 16384
  int row = blockIdx.x * 2 + (threadIdx.x >> 7);
  int d = threadIdx.x & 127;
  float ltot = 0.0f, o = 0.0f;
#pragma unroll
  for (int i = 0; i < NSPLIT; ++i) {
    ltot += pL[(long)i * R + row];
    o += pO[((long)i * R + row) * 128 + d];
  }
  o /= ltot;
  int bh = row >> 9, q = row & 511;
  int b = bh >> 4, h = bh & 15;
  attb[(((long)(b * 512 + q) * 16 + h)) * 128 + d] = f2bf(o);
}

// ---------------------------------------------------------------------------
extern "C" void kernel_launch(void* const* d_in, const int* in_sizes, int n_in,
                              void* d_out, int out_size, void* d_ws, size_t ws_size,
                              hipStream_t stream) {
  const float* draft = (const float*)d_in[0];
  const float* ctx = (const float*)d_in[1];
  const float* Wq = (const float*)d_in[2];
  const float* Wk = (const float*)d_in[3];
  const float* Wv = (const float*)d_in[4];
  const float* Wo = (const float*)d_in[5];
  const float* qw = (const float*)d_in[6];
  const float* kw = (const float*)d_in[7];
  const int* cpos = (const int*)d_in[8];
  const int* dpos = (const int*)d_in[9];

  char* ws = (char*)d_ws;
  unsigned short* kvb = (unsigned short*)(ws + 0);          // 37,748,736
  unsigned short* wqb = (unsigned short*)(ws + 37748736);   //  8,388,608
  unsigned short* wkb = (unsigned short*)(ws + 46137344);   //  2,097,152 \ adjacent =
  unsigned short* wvb = (unsigned short*)(ws + 48234496);   //  2,097,152 / wkvb[1024,2048]
  unsigned short* wob = (unsigned short*)(ws + 50331648);   //  8,388,608
  float* qraw = (float*)(ws + 58720256);                    //  8,388,608
  float* kvraw = (float*)(ws + 67108864);                   // 37,748,736 (K cols only; dead after post)
  float* pO = (float*)(ws + 67108864);                      // 33,554,432 (aliases kvraw)
  float* pL = (float*)(ws + 100663296);                     //     262,144
  unsigned short* qatt = (unsigned short*)(ws + 104857600); //  4,194,304
  unsigned short* katt = (unsigned short*)(ws + 109051904); //  9,437,184
  unsigned short* vtb = (unsigned short*)(ws + 118489088);  //  9,437,184
  unsigned short* attb = (unsigned short*)(ws + 127926272); //  4,194,304
  // total 132,120,576 B

  // 1. convert inputs/weights to bf16 (kv = context||draft per batch)
  conv_kernel<<<dim3(14336), 256, 0, stream>>>(ctx, draft, Wq, Wk, Wv, Wo, kvb, wqb,
                                               wkb, wvb, wob);
  // 2. Q/K/V projections (48 KB LDS, 3 blocks/CU); V fused transpose epilogue
  qkv_kernel<<<dim3(704), 256, 0, stream>>>(kvb, wqb, wkb, qraw, kvraw, vtb);
  // 3. RMSNorm+RoPE for Q,K only
  post_kernel<<<dim3(13312), 256, 0, stream>>>(qraw, kvraw, qw, kw, cpos, dpos, qatt,
                                               katt);
  // 4. attention: 256 blocks x 512 threads, split-K x4
  attn_kernel<<<dim3(256), 512, 0, stream>>>(qatt, katt, vtb, pO, pL);
  // 5. combine partials (plain sum)
  acomb_kernel<<<dim3(8192), 256, 0, stream>>>(pO, pL, attb);
  // 6. out = attn @ Wo^T, direct 64x64 tiles
  ogemm_kernel<<<dim3(512), 256, 0, stream>>>(attb, wob, (float*)d_out);
}